// Round 7
// baseline (358.741 us; speedup 1.0000x reference)
//
#include <hip/hip_runtime.h>

// FFLayer: out = relu( (x / (||x||_2 + 1e-4)) @ W^T + b )
// x: [131072,1024] f32, W: [256,1024] f32, b: [256] f32, out: [131072,256] f32
//
// Round 7: B-from-L2 (no B LDS at all; Wb=512KB is L2-resident), A-only LDS
// double-buffer via global_load_lds (proven path), plain __syncthreads.
// 512 threads, BM=64, BK=32, 2 blocks/CU (34KB LDS), 8 waves = 2(M)x4(N),
// wave tile 32x64. LDS traffic/step = A 8KB staged + 32KB read (0.5KB/row).
// Two resident blocks decorrelate barrier phases -> HBM/LDS/VALU overlap.

#define IN_F   1024
#define OUT_F  256
#define BATCH  131072
#define BM     64
#define BK     32
#define NKT    32
#define EPSV   1e-4f

typedef __attribute__((ext_vector_type(8))) __bf16 bf16x8;
typedef __attribute__((ext_vector_type(4))) __bf16 bf16x4;
typedef __attribute__((ext_vector_type(4))) float  f32x4;

__device__ __forceinline__ void gload_lds16(const void* g, void* lds) {
  __builtin_amdgcn_global_load_lds(
      (const __attribute__((address_space(1))) void*)g,
      (__attribute__((address_space(3))) void*)lds, 16, 0, 0);
}

// W (f32 [256][1024]) -> bf16 [256][1024] in d_ws (512 KB)
__global__ void wconv_kernel(const float* __restrict__ W, __bf16* __restrict__ Wb) {
  const int t = blockIdx.x * blockDim.x + threadIdx.x;
  const float4 v = reinterpret_cast<const float4*>(W)[t];
  bf16x4 h;
  h[0] = (__bf16)v.x; h[1] = (__bf16)v.y; h[2] = (__bf16)v.z; h[3] = (__bf16)v.w;
  reinterpret_cast<bf16x4*>(Wb)[t] = h;
}

__global__ __launch_bounds__(512, 2)
void ffl_kernel(const float* __restrict__ x, const __bf16* __restrict__ Wb,
                const float* __restrict__ bias, float* __restrict__ out) {
  // smem: A bufs 2 x 8KB at 0/8192 (loop); epilogue stg [64][132] f32 =
  // 33792 B reuses [0,33792); norms[64] at 33792. Total 34048 -> 2 blocks/CU.
  __shared__ __align__(16) char smem[34048];
  char* const Ab[2] = {smem, smem + 8192};

  const int tid  = threadIdx.x;
  const int lane = tid & 63;
  const int wave = tid >> 6;     // 8 waves: 2(M) x 4(N)
  const int wr   = wave >> 2;
  const int wc   = wave & 3;
  const int rm   = lane & 15;
  const int q    = lane >> 4;
  const size_t block_row = (size_t)blockIdx.x * BM;

  // ---- A staging: 1 gload_lds/thread/step. Wave w stages rows 8w..8w+7
  //      (1KB chunk, linear by lane); source granule pre-swizzled by row&7.
  const int arow = 8 * wave + (lane >> 3);
  const int asg  = (lane & 7) ^ (arow & 7);
  const float* aSrc = x + (block_row + arow) * IN_F + asg * 4;
  const int aDst = wave * 1024;

  // ---- B direct from L2: lane reads Wb row (wc*64 + n*16 + rm), 16B at
  //      k-granule q*8 (64B/row x 16 rows per load -> L2-friendly).
  const __bf16* bp = Wb + (size_t)(wc * 64 + rm) * IN_F + q * 8;

  // bias hoisted
  const int col0 = wc * 64 + rm;
  float bn[4];
  #pragma unroll
  for (int n = 0; n < 4; ++n) bn[n] = bias[col0 + n * 16];

  f32x4 acc[2][4];
  #pragma unroll
  for (int m = 0; m < 2; ++m)
    #pragma unroll
    for (int n = 0; n < 4; ++n)
      acc[m][n] = (f32x4){0.f, 0.f, 0.f, 0.f};

  float ssq0 = 0.f, ssq1 = 0.f;

  // ---------------- prologue ----------------
  gload_lds16(aSrc, Ab[0] + aDst);
  __syncthreads();

  // ---------------- main loop ----------------
  #pragma unroll
  for (int kt = 0; kt < NKT; ++kt) {
    const int cur = kt & 1;
    if (kt + 1 < NKT)
      gload_lds16(aSrc + (kt + 1) * BK, Ab[cur ^ 1] + aDst);

    // B fragments (plain loads; compiler hoists/schedules)
    bf16x8 bF[4];
    #pragma unroll
    for (int n = 0; n < 4; ++n)
      bF[n] = *reinterpret_cast<const bf16x8*>(bp + (size_t)n * 16 * IN_F + kt * BK);

    // A fragments from LDS (f32, swizzled) + exact sumsq + cvt to bf16
    bf16x8 aF[2];
    #pragma unroll
    for (int m = 0; m < 2; ++m) {
      const int ra = wr * 32 + m * 16 + rm;
      const char* ab = Ab[cur] + ra * 128;
      const int sw = ra & 7;
      const f32x4 lo = *reinterpret_cast<const f32x4*>(ab + ((2 * q)     ^ sw) * 16);
      const f32x4 hi = *reinterpret_cast<const f32x4*>(ab + ((2 * q + 1) ^ sw) * 16);
      float& ssq = m ? ssq1 : ssq0;
      ssq += lo[0]*lo[0] + lo[1]*lo[1] + lo[2]*lo[2] + lo[3]*lo[3]
           + hi[0]*hi[0] + hi[1]*hi[1] + hi[2]*hi[2] + hi[3]*hi[3];
      bf16x8 a;
      a[0]=(__bf16)lo[0]; a[1]=(__bf16)lo[1]; a[2]=(__bf16)lo[2]; a[3]=(__bf16)lo[3];
      a[4]=(__bf16)hi[0]; a[5]=(__bf16)hi[1]; a[6]=(__bf16)hi[2]; a[7]=(__bf16)hi[3];
      aF[m] = a;
    }

    #pragma unroll
    for (int n = 0; n < 4; ++n) {
      acc[0][n] = __builtin_amdgcn_mfma_f32_16x16x32_bf16(aF[0], bF[n], acc[0][n], 0, 0, 0);
      acc[1][n] = __builtin_amdgcn_mfma_f32_16x16x32_bf16(aF[1], bF[n], acc[1][n], 0, 0, 0);
    }

    __syncthreads();   // drains A prefetch (vmcnt0) + LDS; 2 blocks/CU overlap
  }

  // ---------------- row L2-norms ----------------
  ssq0 += __shfl_xor(ssq0, 16); ssq0 += __shfl_xor(ssq0, 32);
  ssq1 += __shfl_xor(ssq1, 16); ssq1 += __shfl_xor(ssq1, 32);
  float* norms = reinterpret_cast<float*>(smem + 33792);
  if (wc == 0 && q == 0) {
    norms[wr * 32 + rm]      = 1.0f / (sqrtf(ssq0) + EPSV);
    norms[wr * 32 + 16 + rm] = 1.0f / (sqrtf(ssq1) + EPSV);
  }
  __syncthreads();

  // ---------------- epilogue: 2 rounds of 128 cols (stg = [64][132] f32) ----
  float* stg = reinterpret_cast<float*>(smem);
  const int r = tid >> 3, p = tid & 7;       // store coords: 8 threads/row
  float* orow = out + (block_row + r) * OUT_F;
  #pragma unroll
  for (int half = 0; half < 2; ++half) {
    if ((wc >> 1) == half) {
      const int cl = (wc & 1) * 64 + rm;     // local col within this half
      #pragma unroll
      for (int n = 0; n < 4; ++n) {
        #pragma unroll
        for (int m = 0; m < 2; ++m) {
          #pragma unroll
          for (int j = 0; j < 4; ++j) {
            const int lr = wr * 32 + m * 16 + q * 4 + j;
            stg[lr * 132 + cl + n * 16] = fmaxf(acc[m][n][j] * norms[lr] + bn[n], 0.f);
          }
        }
      }
    }
    __syncthreads();
    // store this half: 64 rows x 128 cols, full 128B lines
    #pragma unroll
    for (int i = 0; i < 4; ++i) {
      const int f = i * 8 + p;               // f32x4 index within 128 cols
      const f32x4 v = *reinterpret_cast<const f32x4*>(stg + r * 132 + f * 4);
      *reinterpret_cast<f32x4*>(orow + half * 128 + f * 4) = v;
    }
    __syncthreads();
  }
}

extern "C" void kernel_launch(void* const* d_in, const int* in_sizes, int n_in,
                              void* d_out, int out_size, void* d_ws, size_t ws_size,
                              hipStream_t stream) {
  const float* x = (const float*)d_in[0];
  const float* W = (const float*)d_in[1];
  const float* b = (const float*)d_in[2];
  float* out = (float*)d_out;
  __bf16* Wb = (__bf16*)d_ws;   // 512 KB scratch

  wconv_kernel<<<(OUT_F * IN_F / 4) / 256, 256, 0, stream>>>(W, Wb);
  ffl_kernel<<<BATCH / BM, 512, 0, stream>>>(x, Wb, b, out);
}

// Round 8
// 170.625 us; speedup vs baseline: 2.1025x; 2.1025x over previous
//
#include <hip/hip_runtime.h>

// FFLayer: out = relu( (x / (||x||_2 + 1e-4)) @ W^T + b )
// x: [131072,1024] f32, W: [256,1024] f32, b: [256] f32, out: [131072,256] f32
//
// Round 8 = round 6 skeleton (all staging via global_load_lds, counted vmcnt,
// raw s_barrier, 1024 thr, BM=128, 16 waves of 32x64) plus:
//  (a) per-block K-rotation (phase = blockIdx&15) -> DRAM channel spread
//  (b) B 4-deep (LDS = 160KB exactly), waits vmcnt(6)/(4) even/odd,
//      tail 4,1,0,0 -> 2 B-tiles + 1 A-group in flight across every barrier.

#define IN_F   1024
#define OUT_F  256
#define BATCH  131072
#define BM     128
#define NKT    32      // BK=32 compute steps
#define EPSV   1e-4f

typedef __attribute__((ext_vector_type(8))) __bf16 bf16x8;
typedef __attribute__((ext_vector_type(4))) __bf16 bf16x4;
typedef __attribute__((ext_vector_type(4))) float  f32x4;

__device__ __forceinline__ void gload_lds16(const void* g, void* lds) {
  __builtin_amdgcn_global_load_lds(
      (const __attribute__((address_space(1))) void*)g,
      (__attribute__((address_space(3))) void*)lds, 16, 0, 0);
}

#define VM_WAIT(N) do { asm volatile("s_waitcnt vmcnt(" #N ")" ::: "memory"); \
                        __builtin_amdgcn_sched_barrier(0); } while (0)

// W (f32 [256][1024]) -> bf16 [256][1024] in d_ws (512 KB)
__global__ void wconv_kernel(const float* __restrict__ W, __bf16* __restrict__ Wb) {
  const int t = blockIdx.x * blockDim.x + threadIdx.x;
  const float4 v = reinterpret_cast<const float4*>(W)[t];
  bf16x4 h;
  h[0] = (__bf16)v.x; h[1] = (__bf16)v.y; h[2] = (__bf16)v.z; h[3] = (__bf16)v.w;
  reinterpret_cast<bf16x4*>(Wb)[t] = h;
}

__global__ __launch_bounds__(1024, 4)
void ffl_kernel(const float* __restrict__ x, const __bf16* __restrict__ Wb,
                const float* __restrict__ bias, float* __restrict__ out) {
  // A bufs: 3 x 32KB at 0/32768/65536 (f32, [128 rows][256B], granule-swizzled)
  // B bufs: 4 x 16KB at 98304..163840 (bf16, [256 rows][64B], swizzled)
  // norms: 512B at 163328 (inside B[3], retired after loop)
  // Epilogue stg [128][260] f32 = 133120B reuses [0,133120).
  __shared__ __align__(16) char smem[163840];
  char* const Ab[3] = {smem, smem + 32768, smem + 65536};
  char* const Bb[4] = {smem + 98304, smem + 114688, smem + 131072, smem + 147456};

  const int tid  = threadIdx.x;
  const int lane = tid & 63;
  const int wave = tid >> 6;     // 16 waves: 4(M) x 4(N)
  const int wr   = wave >> 2;
  const int wc   = wave & 3;
  const int rm   = lane & 15;
  const int q    = lane >> 4;
  const size_t block_row = (size_t)blockIdx.x * BM;
  const int phg = blockIdx.x & 15;            // K-rotation phase (A-groups)

  // ---- A staging: 2 issues/thread/group. Chunk c=2w+i (1KB = 4 rows x 256B).
  const float* aSrc[2]; int aDst[2];
  #pragma unroll
  for (int i = 0; i < 2; ++i) {
    const int c   = 2 * wave + i;
    const int row = 4 * c + (lane >> 4);
    const int s   = (lane & 15) ^ (row & 7);
    aSrc[i] = x + (block_row + row) * IN_F + s * 4;
    aDst[i] = c * 1024;
  }
  // ---- B staging: 1 issue/thread/step. Chunk = wave (1KB = 16 rows x 64B).
  const int brow = 16 * wave + (lane >> 2);
  const int bs   = (lane & 3) ^ ((brow >> 1) & 3);
  const __bf16* bSrc = Wb + (size_t)brow * IN_F + bs * 8;
  const int bDst = wave * 1024;

  f32x4 acc[2][4];
  #pragma unroll
  for (int m = 0; m < 2; ++m)
    #pragma unroll
    for (int n = 0; n < 4; ++n)
      acc[m][n] = (f32x4){0.f, 0.f, 0.f, 0.f};

  float ssq0 = 0.f, ssq1 = 0.f;

  auto stageA = [&](int g) {      // logical group g -> physical (g+phg)&15
    const int pg = (g + phg) & 15;
    gload_lds16(aSrc[0] + pg * 64, Ab[g % 3] + aDst[0]);
    gload_lds16(aSrc[1] + pg * 64, Ab[g % 3] + aDst[1]);
  };
  auto stageB = [&](int kt) {     // logical step -> physical (kt+2*phg)&31
    const int pk = (kt + 2 * phg) & 31;
    gload_lds16(bSrc + pk * 32, Bb[kt & 3] + bDst);
  };

  // -------- prologue: A(g0) A(g1) B0 B1 B2 in flight --------
  stageA(0);
  stageA(1);
  stageB(0);
  stageB(1);
  stageB(2);
  VM_WAIT(2);                    // A0,A1,B0 landed; B1,B2 in flight
  __builtin_amdgcn_s_barrier();

  // -------- main loop: 32 steps of BK=32 --------
  #pragma unroll
  for (int kt = 0; kt < NKT; ++kt) {
    if (kt + 3 < NKT) stageB(kt + 3);
    if ((kt & 1) == 0 && (kt / 2 + 2) < 16) stageA(kt / 2 + 2);

    const char* abuf = Ab[(kt >> 1) % 3];
    const char* bbuf = Bb[kt & 3];
    const int   gb   = (kt & 1) * 8 + 2 * q;   // A granule base within 256B row

    // A fragments (f32 -> bf16) + exact sumsq
    bf16x8 aF[2];
    #pragma unroll
    for (int m = 0; m < 2; ++m) {
      const int ra = wr * 32 + m * 16 + rm;
      const char* ab = abuf + ra * 256;
      const int sw = ra & 7;
      const f32x4 lo = *reinterpret_cast<const f32x4*>(ab + ((gb)     ^ sw) * 16);
      const f32x4 hi = *reinterpret_cast<const f32x4*>(ab + ((gb + 1) ^ sw) * 16);
      float& ssq = m ? ssq1 : ssq0;
      ssq += lo[0]*lo[0] + lo[1]*lo[1] + lo[2]*lo[2] + lo[3]*lo[3]
           + hi[0]*hi[0] + hi[1]*hi[1] + hi[2]*hi[2] + hi[3]*hi[3];
      bf16x8 a;
      a[0]=(__bf16)lo[0]; a[1]=(__bf16)lo[1]; a[2]=(__bf16)lo[2]; a[3]=(__bf16)lo[3];
      a[4]=(__bf16)hi[0]; a[5]=(__bf16)hi[1]; a[6]=(__bf16)hi[2]; a[7]=(__bf16)hi[3];
      aF[m] = a;
    }

    #pragma unroll
    for (int n = 0; n < 4; ++n) {
      const int rb = wc * 64 + n * 16 + rm;
      const bf16x8 bF = *reinterpret_cast<const bf16x8*>(
          bbuf + rb * 64 + (q ^ ((rb >> 1) & 3)) * 16);
      acc[0][n] = __builtin_amdgcn_mfma_f32_16x16x32_bf16(aF[0], bF, acc[0][n], 0, 0, 0);
      acc[1][n] = __builtin_amdgcn_mfma_f32_16x16x32_bf16(aF[1], bF, acc[1][n], 0, 0, 0);
    }

    // FIFO-simulated waits (see derivation): steady even->6, odd->4;
    // startup kt=0 ->4; tail kt=28->4, kt=29->1, kt>=30->0.
    if (kt == 29)                              { VM_WAIT(1); }
    else if (kt >= 30)                         { VM_WAIT(0); }
    else if (kt == 0 || kt == 28 || (kt & 1))  { VM_WAIT(4); }
    else                                       { VM_WAIT(6); }
    __builtin_amdgcn_s_barrier();
  }

  // -------- row L2-norms --------
  ssq0 += __shfl_xor(ssq0, 16); ssq0 += __shfl_xor(ssq0, 32);
  ssq1 += __shfl_xor(ssq1, 16); ssq1 += __shfl_xor(ssq1, 32);
  float* norms = reinterpret_cast<float*>(smem + 163328);
  if (wc == 0 && q == 0) {
    norms[wr * 32 + rm]      = 1.0f / (sqrtf(ssq0) + EPSV);
    norms[wr * 32 + 16 + rm] = 1.0f / (sqrtf(ssq1) + EPSV);
  }
  __syncthreads();

  // -------- scale + bias + relu -> LDS transpose --------
  float* stg = reinterpret_cast<float*>(smem);   // [128][260] f32 = 133120B
  const int col0 = wc * 64 + rm;
  #pragma unroll
  for (int n = 0; n < 4; ++n) {
    const float bn = bias[col0 + n * 16];
    #pragma unroll
    for (int m = 0; m < 2; ++m) {
      #pragma unroll
      for (int j = 0; j < 4; ++j) {
        const int lr = wr * 32 + m * 16 + q * 4 + j;
        stg[lr * 260 + col0 + n * 16] = fmaxf(acc[m][n][j] * norms[lr] + bn, 0.f);
      }
    }
  }
  __syncthreads();

  // -------- coalesced store: full 128B lines --------
  const int r = tid >> 3, p = tid & 7;       // 128 rows, 8 threads/row
  const float* srow = stg + r * 260;
  float* orow = out + (block_row + r) * OUT_F;
  #pragma unroll
  for (int i = 0; i < 8; ++i) {
    const int f = i * 8 + p;
    const f32x4 v = *reinterpret_cast<const f32x4*>(srow + f * 4);
    *reinterpret_cast<f32x4*>(orow + f * 4) = v;
  }
}

extern "C" void kernel_launch(void* const* d_in, const int* in_sizes, int n_in,
                              void* d_out, int out_size, void* d_ws, size_t ws_size,
                              hipStream_t stream) {
  const float* x = (const float*)d_in[0];
  const float* W = (const float*)d_in[1];
  const float* b = (const float*)d_in[2];
  float* out = (float*)d_out;
  __bf16* Wb = (__bf16*)d_ws;   // 512 KB scratch

  wconv_kernel<<<(OUT_F * IN_F / 4) / 256, 256, 0, stream>>>(W, Wb);
  ffl_kernel<<<BATCH / BM, 1024, 0, stream>>>(x, Wb, b, out);
}